// Round 24
// baseline (266.326 us; speedup 1.0000x reference)
//
#include <hip/hip_runtime.h>

#define SEQ   2048
#define EMB   2048
#define NHEAD 16
#define HDIM  128
#define ROWSM 4096  // B*SEQ

typedef float  f32x4   __attribute__((ext_vector_type(4)));
typedef float  f32x16  __attribute__((ext_vector_type(16)));
typedef __bf16 bf16x8  __attribute__((ext_vector_type(8)));

__device__ __forceinline__ unsigned short f2bf(float f) {
  union { __bf16 b; unsigned short u; } v; v.b = (__bf16)f; return v.u;
}
__device__ __forceinline__ unsigned int pk2(float a, float b) {
  return (unsigned int)f2bf(a) | ((unsigned int)f2bf(b) << 16);
}
__device__ __forceinline__ float max3f(float a, float b, float c) {
  return fmaxf(fmaxf(a, b), c);   // clang fuses to v_max3_f32 (T17)
}

__device__ __forceinline__ void gload16(const void* g, void* l) {
  __builtin_amdgcn_global_load_lds(
      (__attribute__((address_space(1))) const unsigned int*)g,
      (__attribute__((address_space(3))) unsigned int*)l,
      16, 0, 0);
}

// ALL fp32->bf16 converts in ONE launch (round-18 proven, frozen)
__global__ void cvt_all(const float* __restrict__ x,  const float* __restrict__ Wq,
                        const float* __restrict__ Wk, const float* __restrict__ Wv,
                        const float* __restrict__ Wp, unsigned short* __restrict__ xb,
                        unsigned short* __restrict__ WB3, unsigned short* __restrict__ Wb,
                        int nX4, int nW4) {
  const int z = blockIdx.z;
  const float* in;
  unsigned short* out;
  int n4;
  if (z == 0)      { in = x;  out = xb;  n4 = nX4; }
  else if (z == 1) { in = Wq; out = WB3;                          n4 = nW4; }
  else if (z == 2) { in = Wk; out = WB3 + (size_t)EMB * EMB;      n4 = nW4; }
  else if (z == 3) { in = Wv; out = WB3 + (size_t)2 * EMB * EMB;  n4 = nW4; }
  else             { in = Wp; out = Wb;  n4 = nW4; }
  int i = blockIdx.x * 256 + threadIdx.x;
  if (i >= n4) return;
  float4 v = ((const float4*)in)[i];
  ushort4 o4;
  o4.x = f2bf(v.x); o4.y = f2bf(v.y); o4.z = f2bf(v.z); o4.w = f2bf(v.w);
  ((ushort4*)out)[i] = o4;
}

// ====== QKV fused GEMM: BM=256 x BN=192, N=6144 — THIS ROUND: 32x32x16 MFMA.
// Same tile/stage/ledger/swizzle as the round-17-proven kernel; only the wave
// decomposition (4m x 2n -> per-wave 64x96), fragment reads, and epilogue
// C-map change. 24 MFMA/K-tile of 32x32x16 (vs 48 of 16x16x32): -17% MFMA
// pipe time for the same FLOP (8.07cy/32k vs 4.85cy/16k, m119), fewer issues.
// All three fragment layouts are session-proven in the passing attn kernel:
// A/B: lane holds row/col=lane&31, k=(lane>>5)*8+j; C: row=(r&3)+8(r>>2)+4*hi,
// col=lane&31. Staging regions re-mapped to row-bit5 parity so ph0 reads
// exactly Aeven (rows wr*64+[0,32): bit5=0) and ph1 Aodd. vmcnt ledger
// UNCHANGED: prologue 12, retire 5 (vmcnt7); ph0 stages Aodd(t+1)[2], end
// vmcnt(7) retires Aodd(t); ph1 stages Ae(t+2)+B(t+2)[5], end vmcnt(7)
// retires Ae+B(t+1); tail 7->2->0, never a mid-loop drain (T4).
__global__ __launch_bounds__(512, 1) void gemm192_qkv(
    const unsigned short* __restrict__ A, const unsigned short* __restrict__ B,
    unsigned short* __restrict__ Cb) {
  __shared__ __align__(16) unsigned short At[2][256 * 64];  // 64KB
  __shared__ __align__(16) unsigned short Bt[2][192 * 64];  // 48KB

  const int tid  = threadIdx.x;
  const int lane = tid & 63;
  const int w    = tid >> 6;        // 0..7
  const int wr   = w >> 1;          // 0..3  (m quarter: 64 rows)
  const int wc   = w & 1;           // 0..1  (n half: 96 cols)
  const int l31  = lane & 31;
  const int l5   = lane >> 5;       // 0/1

  const int bid = blockIdx.x;
  const int xcd = bid & 7;
  const int j   = bid >> 3;
  const int mt  = xcd * 2 + (j >> 5);
  const int nt  = j & 31;
  const int m0 = mt * 256;
  const int n0 = nt * 192;

  const int srow8 = lane >> 3;
  const int sslot = (lane & 7) ^ srow8;   // pre-swizzled global 16B slot
  const int NT = EMB / 64;                // 32 K-tiles

  // Aeven = rows with (row>>5)&1==0 -> chunks {0-3,8-11,16-19,24-27}
  auto stageAeven = [&](int ts) {
    if (ts >= NT) return;
    int buf = ts & 1, k0 = ts * 64;
    { int c = (w >> 2) * 8 + (w & 3);      int row = c * 8 + srow8;
      gload16(A + (size_t)(m0 + row) * EMB + k0 + sslot * 8, (char*)&At[buf][0] + c * 1024); }
    { int c = (w >> 2) * 8 + (w & 3) + 16; int row = c * 8 + srow8;
      gload16(A + (size_t)(m0 + row) * EMB + k0 + sslot * 8, (char*)&At[buf][0] + c * 1024); }
  };
  auto stageAodd = [&](int ts) {          // rows with (row>>5)&1==1 -> +4 chunks
    if (ts >= NT) return;
    int buf = ts & 1, k0 = ts * 64;
    { int c = (w >> 2) * 8 + (w & 3) + 4;  int row = c * 8 + srow8;
      gload16(A + (size_t)(m0 + row) * EMB + k0 + sslot * 8, (char*)&At[buf][0] + c * 1024); }
    { int c = (w >> 2) * 8 + (w & 3) + 20; int row = c * 8 + srow8;
      gload16(A + (size_t)(m0 + row) * EMB + k0 + sslot * 8, (char*)&At[buf][0] + c * 1024); }
  };
  auto stageB = [&](int ts) {             // 192 rows = chunks 0-23, 3 sweeps
    if (ts >= NT) return;
    int buf = ts & 1, k0 = ts * 64;
#pragma unroll
    for (int s = 0; s < 3; ++s) {
      int c = w + s * 8;
      int row = c * 8 + srow8;
      gload16(B + (size_t)(n0 + row) * EMB + k0 + sslot * 8, (char*)&Bt[buf][0] + c * 1024);
    }
  };

  f32x16 acc[2][3] = {};                  // [mf][nf], 32x32 frags
  bf16x8 afr[4], bfr[3][4];               // [kk] / [nf][kk], K=16 per step

  stageAeven(0); stageB(0); stageAodd(0); stageAeven(1); stageB(1);
  asm volatile("s_waitcnt vmcnt(7)" ::: "memory");
  __builtin_amdgcn_s_barrier();

  for (int t = 0; t < NT; ++t) {
    const char* ab = (const char*)&At[t & 1][0];
    const char* bb = (const char*)&Bt[t & 1][0];

    // ---------- phase 0: mf0 (A rows wr*64+[0,32), bit5=0) x all B ----------
#pragma unroll
    for (int nf = 0; nf < 3; ++nf)
#pragma unroll
      for (int kk = 0; kk < 4; ++kk) {
        int row = wc * 96 + nf * 32 + l31;
        bfr[nf][kk] = *(const bf16x8*)(bb + row * 128 + ((((kk << 1) | l5) ^ (row & 7)) << 4));
      }
#pragma unroll
    for (int kk = 0; kk < 4; ++kk) {
      int row = wr * 64 + l31;
      afr[kk] = *(const bf16x8*)(ab + row * 128 + ((((kk << 1) | l5) ^ (row & 7)) << 4));
    }
    stageAodd(t + 1);
    __builtin_amdgcn_s_barrier();
    asm volatile("s_waitcnt lgkmcnt(0)" ::: "memory");
    __builtin_amdgcn_sched_barrier(0);
    __builtin_amdgcn_s_setprio(1);
#pragma unroll
    for (int nf = 0; nf < 3; ++nf)
#pragma unroll
      for (int kk = 0; kk < 4; ++kk)
        acc[0][nf] = __builtin_amdgcn_mfma_f32_32x32x16_bf16(
            afr[kk], bfr[nf][kk], acc[0][nf], 0, 0, 0);
    __builtin_amdgcn_s_setprio(0);
    if (t + 1 < NT) asm volatile("s_waitcnt vmcnt(7)" ::: "memory");
    else            asm volatile("s_waitcnt vmcnt(0)" ::: "memory");
    __builtin_amdgcn_s_barrier();

    // ---------- phase 1: mf1 (A rows wr*64+[32,64), bit5=1) x B (regs) ------
#pragma unroll
    for (int kk = 0; kk < 4; ++kk) {
      int row = wr * 64 + 32 + l31;
      afr[kk] = *(const bf16x8*)(ab + row * 128 + ((((kk << 1) | l5) ^ (row & 7)) << 4));
    }
    stageAeven(t + 2); stageB(t + 2);
    __builtin_amdgcn_s_barrier();
    asm volatile("s_waitcnt lgkmcnt(0)" ::: "memory");
    __builtin_amdgcn_sched_barrier(0);
    __builtin_amdgcn_s_setprio(1);
#pragma unroll
    for (int nf = 0; nf < 3; ++nf)
#pragma unroll
      for (int kk = 0; kk < 4; ++kk)
        acc[1][nf] = __builtin_amdgcn_mfma_f32_32x32x16_bf16(
            afr[kk], bfr[nf][kk], acc[1][nf], 0, 0, 0);
    __builtin_amdgcn_s_setprio(0);
    if (t + 2 < NT)      asm volatile("s_waitcnt vmcnt(7)" ::: "memory");
    else if (t + 1 < NT) asm volatile("s_waitcnt vmcnt(2)" ::: "memory");
    __builtin_amdgcn_s_barrier();
  }

  // epilogue: 32x32 C-map (attn-proven): row=(r&3)+8*(r>>2)+4*l5, col=l31
#pragma unroll
  for (int mf = 0; mf < 2; ++mf)
#pragma unroll
    for (int nf = 0; nf < 3; ++nf) {
      int col = n0 + wc * 96 + nf * 32 + l31;
      unsigned short* dst = Cb + (size_t)(col >> 11) * ROWSM * EMB + (col & 2047);
#pragma unroll
      for (int r = 0; r < 16; ++r) {
        int row = m0 + wr * 64 + mf * 32 + (r & 3) + 8 * (r >> 2) + 4 * l5;
        dst[(size_t)row * EMB] = f2bf(acc[mf][nf][r]);
      }
    }
}

// ====== Final projection GEMM: BM=128 x BN=256 (round-15 proven, frozen) =====
__global__ __launch_bounds__(512, 1) void gemm_p8(
    const unsigned short* __restrict__ A, const unsigned short* __restrict__ B,
    float* __restrict__ Cout, const float* __restrict__ bias) {
  __shared__ __align__(16) unsigned short At[2][128 * 64];
  __shared__ __align__(16) unsigned short Bt[2][256 * 64];

  const int tid  = threadIdx.x;
  const int lane = tid & 63;
  const int w    = tid >> 6;
  const int wr   = w >> 2;
  const int wc   = w & 3;
  const int lg   = lane >> 4;
  const int lc   = lane & 15;

  const int bid = blockIdx.x;
  const int xcd = bid & 7;
  const int j   = bid >> 3;
  const int mt  = xcd * 4 + (j >> 3);
  const int nt  = j & 7;
  const int m0 = mt * 128;
  const int n0 = nt * 256;

  const int srow8 = lane >> 3;
  const int sslot = (lane & 7) ^ srow8;
  const int NT = EMB / 64;

  auto stageA = [&](int ts) {
    if (ts >= NT) return;
    int buf = ts & 1, k0 = ts * 64;
#pragma unroll
    for (int rr = 0; rr < 2; ++rr) {
      int c = w + rr * 8;
      int row = c * 8 + srow8;
      gload16(A + (size_t)(m0 + row) * EMB + k0 + sslot * 8, (char*)&At[buf][0] + c * 1024);
    }
  };
  auto stageBlow = [&](int ts) {
    if (ts >= NT) return;
    int buf = ts & 1, k0 = ts * 64;
#pragma unroll
    for (int rr = 0; rr < 2; ++rr) {
      int i = w + rr * 8;
      int c = (i >> 2) * 8 + (i & 3);
      int row = c * 8 + srow8;
      gload16(B + (size_t)(n0 + row) * EMB + k0 + sslot * 8, (char*)&Bt[buf][0] + c * 1024);
    }
  };
  auto stageBhigh = [&](int ts) {
    if (ts >= NT) return;
    int buf = ts & 1, k0 = ts * 64;
#pragma unroll
    for (int rr = 0; rr < 2; ++rr) {
      int i = w + rr * 8;
      int c = (i >> 2) * 8 + 4 + (i & 3);
      int row = c * 8 + srow8;
      gload16(B + (size_t)(n0 + row) * EMB + k0 + sslot * 8, (char*)&Bt[buf][0] + c * 1024);
    }
  };

  f32x4 acc[4][4] = {};
  bf16x8 afr[4][2], bfr0[2][2], bfr1[2][2];

  stageA(0); stageBlow(0); stageBhigh(0); stageA(1); stageBlow(1);
  asm volatile("s_waitcnt vmcnt(6)" ::: "memory");
  __builtin_amdgcn_s_barrier();

  for (int t = 0; t < NT; ++t) {
    const char* ab = (const char*)&At[t & 1][0];
    const char* bb = (const char*)&Bt[t & 1][0];

#pragma unroll
    for (int ni = 0; ni < 2; ++ni)
#pragma unroll
      for (int kk = 0; kk < 2; ++kk) {
        int row = wc * 64 + ni * 16 + lc;
        bfr0[ni][kk] = *(const bf16x8*)(bb + row * 128 + ((((kk << 2) | lg) ^ (lc & 7)) << 4));
      }
#pragma unroll
    for (int mi = 0; mi < 4; ++mi)
#pragma unroll
      for (int kk = 0; kk < 2; ++kk) {
        int row = wr * 64 + mi * 16 + lc;
        afr[mi][kk] = *(const bf16x8*)(ab + row * 128 + ((((kk << 2) | lg) ^ (lc & 7)) << 4));
      }
    stageBhigh(t + 1);
    __builtin_amdgcn_s_barrier();
    asm volatile("s_waitcnt lgkmcnt(0)" ::: "memory");
    __builtin_amdgcn_sched_barrier(0);
    __builtin_amdgcn_s_setprio(1);
#pragma unroll
    for (int mi = 0; mi < 4; ++mi)
#pragma unroll
      for (int ni = 0; ni < 2; ++ni)
#pragma unroll
        for (int kk = 0; kk < 2; ++kk)
          acc[mi][ni] = __builtin_amdgcn_mfma_f32_16x16x32_bf16(
              afr[mi][kk], bfr0[ni][kk], acc[mi][ni], 0, 0, 0);
    __builtin_amdgcn_s_setprio(0);
    if (t + 1 < NT) asm volatile("s_waitcnt vmcnt(6)" ::: "memory");
    else            asm volatile("s_waitcnt vmcnt(0)" ::: "memory");
    __builtin_amdgcn_s_barrier();

#pragma unroll
    for (int ni = 0; ni < 2; ++ni)
#pragma unroll
      for (int kk = 0; kk < 2; ++kk) {
        int row = wc * 64 + 32 + ni * 16 + lc;
        bfr1[ni][kk] = *(const bf16x8*)(bb + row * 128 + ((((kk << 2) | lg) ^ (lc & 7)) << 4));
      }
    stageA(t + 2); stageBlow(t + 2);
    __builtin_amdgcn_s_barrier();
    asm volatile("s_waitcnt lgkmcnt(0)" ::: "memory");
    __builtin_amdgcn_sched_barrier(0);
    __builtin_amdgcn_s_setprio(1);
#pragma unroll
    for (int mi = 0; mi < 4; ++mi)
#pragma unroll
      for (int ni = 0; ni < 2; ++ni)
#pragma unroll
        for (int kk = 0; kk < 2; ++kk)
          acc[mi][2 + ni] = __builtin_amdgcn_mfma_f32_16x16x32_bf16(
              afr[mi][kk], bfr1[ni][kk], acc[mi][2 + ni], 0, 0, 0);
    __builtin_amdgcn_s_setprio(0);
    if (t + 2 < NT)      asm volatile("s_waitcnt vmcnt(6)" ::: "memory");
    else if (t + 1 < NT) asm volatile("s_waitcnt vmcnt(2)" ::: "memory");
    __builtin_amdgcn_s_barrier();
  }

#pragma unroll
  for (int mi = 0; mi < 4; ++mi)
#pragma unroll
    for (int ni = 0; ni < 4; ++ni) {
      int col = n0 + wc * 64 + ((ni >> 1) * 32) + (ni & 1) * 16 + lc;
#pragma unroll
      for (int rr = 0; rr < 4; ++rr) {
        int row = m0 + wr * 64 + mi * 16 + lg * 4 + rr;
        Cout[(size_t)row * EMB + col] = acc[mi][ni][rr] + bias[col];
      }
    }
}

// ====== Causal flash attention (round-21 PASSING 257us state, frozen) ======
__global__ __launch_bounds__(256, 2) void attn_causal(
    const unsigned short* __restrict__ Pq, const unsigned short* __restrict__ Pk,
    const unsigned short* __restrict__ Pv, unsigned short* __restrict__ ctx) {
  __shared__ __align__(16) unsigned short Ks[2][64 * 128];   // swizzled
  __shared__ __align__(16) unsigned short Vt[2][128 * 64];   // swizzled

  const int tid  = threadIdx.x;
  const int lane = tid & 63;
  const int w    = tid >> 6;
  const int ql   = lane & 31;
  const int hi   = lane >> 5;
  const int lg   = lane >> 4;
  const int lc   = lane & 15;

  const int bid = blockIdx.x;
  const int xcd = bid & 7;
  const int jj_ = bid >> 3;
  const int hh  = jj_ >> 4;
  const int bh  = xcd * 4 + hh;
  const int b   = bh >> 4;
  const int h   = bh & 15;
  const int qtr = jj_ & 15;
  const int qt  = (hh >= 2) ? (15 - qtr) : qtr;
  const int q0 = qt * 128;
  const int qw = q0 + w * 32;
  const int qg = qw + ql;

  const size_t hoff = (size_t)bh * SEQ * HDIM;
  const unsigned short* Q  = Pq + hoff;
  const unsigned short* Kh = Pk + hoff;
  const unsigned short* Vh = Pv + hoff;

  bf16x8 bq[8];
#pragma unroll
  for (int d8 = 0; d8 < 8; ++d8)
    bq[d8] = *(const bf16x8*)(Q + (size_t)qg * HDIM + d8 * 16 + hi * 8);

  const float NEG = -3.0e38f;
  f32x16 o[4];
#pragma unroll
  for (int dt = 0; dt < 4; ++dt)
#pragma unroll
    for (int r = 0; r < 16; ++r) o[dt][r] = 0.f;
  float m_r = NEG, l_r = 0.f;

  const float Cs   = 0.12753123161692858f;
  const float TDEF = 62.7f;

  auto stageK = [&](int buf, int t) {
    int kv0 = t * 64;
#pragma unroll
    for (int ii = 0; ii < 4; ++ii) {
      int i = w * 4 + ii;
      int r = i * 4 + lg;
      int sd = lc ^ (r & 7);
      gload16(Kh + (size_t)(kv0 + r) * HDIM + sd * 8, (char*)&Ks[buf][0] + i * 1024);
    }
  };
  auto loadV = [&](uint4* vr, int t) {
    int kv0 = t * 64;
#pragma unroll
    for (int uu = 0; uu < 2; ++uu) {
      int u = tid + uu * 256;
      int kp = u >> 4, dg = u & 15;
      int k = kp * 2, d0 = dg * 8;
      vr[uu * 2]     = *(const uint4*)(Vh + (size_t)(kv0 + k) * HDIM + d0);
      vr[uu * 2 + 1] = *(const uint4*)(Vh + (size_t)(kv0 + k + 1) * HDIM + d0);
    }
  };
  auto packV = [&](int buf, const uint4* vr) {
#pragma unroll
    for (int uu = 0; uu < 2; ++uu) {
      int u = tid + uu * 256;
      int kp = u >> 4, dg = u & 15;
      int k = kp * 2, d0 = dg * 8;
      const unsigned short* e0 = (const unsigned short*)&vr[uu * 2];
      const unsigned short* e1 = (const unsigned short*)&vr[uu * 2 + 1];
#pragma unroll
      for (int jj = 0; jj < 8; ++jj) {
        int d = d0 + jj;
        int slot = (k >> 3) ^ jj ^ (dg & 7);
        int byteoff = d * 128 + (slot << 4) + (k & 7) * 2;
        *(unsigned int*)((char*)&Vt[buf][0] + byteoff) =
            (unsigned int)e0[jj] | ((unsigned int)e1[jj] << 16);
      }
    }
  };

  const int ntiles = 2 * qt + 2;
  uint4 vr[4];

  loadV(vr, 0); stageK(0, 0);
  asm volatile("s_waitcnt vmcnt(4)" ::: "memory");
  packV(0, vr);
  loadV(vr, 1); stageK(1, 1);
  asm volatile("s_waitcnt vmcnt(8)" ::: "memory");
  asm volatile("s_waitcnt lgkmcnt(0)" ::: "memory");
  __builtin_amdgcn_s_barrier();

  for (int t = 0; t < ntiles; ++t) {
    const int buf = t & 1;
    const bool hasN1 = (t + 1 < ntiles);
    const bool hasN2 = (t + 2 < ntiles);
    const int kv0 = t * 64;

    if (hasN1) {
      asm volatile("s_waitcnt vmcnt(4)" ::: "memory");
      packV(buf ^ 1, vr);
      if (hasN2) loadV(vr, t + 2);
    }

    if (kv0 <= qw + 31) {
      const bool s1on = (kv0 + 32 <= qw + 31);
      const bool diag = (kv0 + 63 > qw);
      const char* ksb = (const char*)&Ks[buf][0];
      const char* vtb = (const char*)&Vt[buf][0];

      f32x16 c0, c1;
#pragma unroll
      for (int r = 0; r < 16; ++r) { c0[r] = 0.f; c1[r] = s1on ? 0.f : NEG; }
      __builtin_amdgcn_s_setprio(1);
#pragma unroll
      for (int d8 = 0; d8 < 8; ++d8) {
        bf16x8 ak = *(const bf16x8*)(ksb + ql * 256 +
                                     (((d8 * 2 + hi) ^ (ql & 7)) << 4));
        c0 = __builtin_amdgcn_mfma_f32_32x32x16_bf16(ak, bq[d8], c0, 0, 0, 0);
      }
      if (s1on) {
#pragma unroll
        for (int d8 = 0; d8 < 8; ++d8) {
          bf16x8 ak = *(const bf16x8*)(ksb + (32 + ql) * 256 +
                                       (((d8 * 2 + hi) ^ (ql & 7)) << 4));
          c1 = __builtin_amdgcn_mfma_f32_32x32x16_bf16(ak, bq[d8], c1, 0, 0, 0);
        }
      }
      __builtin_amdgcn_s_setprio(0);

      if (diag) {
#pragma unroll
        for (int r = 0; r < 16; ++r) {
          int kvl = (r & 3) + 8 * (r >> 2) + 4 * hi;
          if (kv0 + kvl > qg) c0[r] = NEG;
          if (s1on && kv0 + 32 + kvl > qg) c1[r] = NEG;
        }
      }
      float rm;
      {
        float a0 = max3f(c0[0],  c0[1],  c0[2]);
        float a1 = max3f(c0[3],  c0[4],  c0[5]);
        float a2 = max3f(c0[6],  c0[7],  c0[8]);
        float a3 = max3f(c0[9],  c0[10], c0[11]);
        float a4 = max3f(c0[12], c0[13], c0[14]);
        float a5 = max3f(c0[15], c1[0],  c1[1]);
        float a6 = max3f(c1[2],  c1[3],  c1[4]);
        float a7 = max3f(c1[5],  c1[6],  c1[7]);
        float a8 = max3f(c1[8],  c1[9],  c1[10]);
        float a9 = max3f(c1[11], c1[12], c1[13]);
        float aa = fmaxf(c1[14], c1[15]);
        float b0 = max3f(a0, a1, a2);
        float b1 = max3f(a3, a4, a5);
        float b2 = max3f(a6, a7, a8);
        float b3 = max3f(a9, aa, NEG);
        rm = fmaxf(fmaxf(b0, b1), fmaxf(b2, b3));
      }
      rm = fmaxf(rm, __shfl_xor(rm, 32));

      if (__any(rm > m_r + TDEF)) {       // T13 defer-max
        float mnew = fmaxf(m_r, rm);
        float alpha = exp2f((m_r - mnew) * Cs);
        m_r = mnew;
        l_r *= alpha;
#pragma unroll
        for (int r = 0; r < 16; ++r) {
          float ar = __shfl(alpha, (r & 3) + 8 * (r >> 2) + 4 * hi);
#pragma unroll
          for (int dt = 0; dt < 4; ++dt) o[dt][r] *= ar;
        }
      }
#pragma unroll
      for (int r = 0; r < 16; ++r) {
        c0[r] = exp2f((c0[r] - m_r) * Cs);
        c1[r] = exp2f((c1[r] - m_r) * Cs);
      }
      float ps = 0.f;
#pragma unroll
      for (int r = 0; r < 16; ++r) ps += c0[r] + c1[r];
      ps += __shfl_xor(ps, 32);
      l_r += ps;

      bf16x8 pa[4];
#pragma unroll
      for (int t4 = 0; t4 < 4; ++t4) {
        const f32x16& cc = (t4 < 2) ? c0 : c1;
        const int rA = (t4 & 1) * 8;
        unsigned int pkL0 = pk2(cc[rA + 0], cc[rA + 1]);
        unsigned int pkL1 = pk2(cc[rA + 2], cc[rA + 3]);
        unsigned int pkH0 = pk2(cc[rA + 4], cc[rA + 5]);
        unsigned int pkH1 = pk2(cc[rA + 6], cc[rA + 7]);
        unsigned int give0 = hi ? pkL0 : pkH0;
        unsigned int give1 = hi ? pkL1 : pkH1;
        unsigned int keep0 = hi ? pkH0 : pkL0;
        unsigned int keep1 = hi ? pkH1 : pkL1;
        unsigned int recv0 = __shfl_xor(give0, 32);
        unsigned int recv1 = __shfl_xor(give1, 32);
        union { unsigned int u[4]; bf16x8 v; } pu;
        pu.u[0] = hi ? recv0 : keep0;
        pu.u[1] = hi ? recv1 : keep1;
        pu.u[2] = hi ? keep0 : recv0;
        pu.u[3] = hi ? keep1 : recv1;
        pa[t4] = pu.v;
      }
      __builtin_amdgcn_s_setprio(1);
#pragma unroll
      for (int t4 = 0; t4 < 4; ++t4) {
        if (diag && kv0 + t4 * 16 > qw + 31) continue;
#pragma unroll
        for (int dt = 0; dt < 4; ++dt) {
          int d = dt * 32 + ql;
          int slot = ((t4 << 1) | hi) ^ (d & 7) ^ ((d >> 3) & 7);
          bf16x8 bv = *(const bf16x8*)(vtb + d * 128 + (slot << 4));
          o[dt] = __builtin_amdgcn_mfma_f32_32x32x16_bf16(pa[t4], bv, o[dt], 0, 0, 0);
        }
      }
      __builtin_amdgcn_s_setprio(0);
    }

    if (hasN2) stageK(buf, t + 2);
    asm volatile("s_waitcnt lgkmcnt(0)" ::: "memory");
    if (hasN1) {
      if (hasN2) asm volatile("s_waitcnt vmcnt(8)" ::: "memory");
      else       asm volatile("s_waitcnt vmcnt(0)" ::: "memory");
    }
    __builtin_amdgcn_s_barrier();
  }

  float linv = 1.0f / l_r;
  unsigned short* outp = ctx + (size_t)b * SEQ * EMB + (size_t)h * HDIM;
#pragma unroll
  for (int r = 0; r < 16; ++r) {
    int kvl = (r & 3) + 8 * (r >> 2) + 4 * hi;
    float lr = __shfl(linv, kvl);
    int qrow = qw + kvl;
#pragma unroll
    for (int dt = 0; dt < 4; ++dt)
      outp[(size_t)qrow * EMB + dt * 32 + ql] = f2bf(o[dt][r] * lr);
  }
}

extern "C" void kernel_launch(void* const* d_in, const int* in_sizes, int n_in,
                              void* d_out, int out_size, void* d_ws, size_t ws_size,
                              hipStream_t stream) {
  const float* x  = (const float*)d_in[0];
  const float* Wq = (const float*)d_in[1];
  const float* Wk = (const float*)d_in[2];
  const float* Wv = (const float*)d_in[3];
  const float* Wp = (const float*)d_in[4];
  const float* bp = (const float*)d_in[5];

  char* ws = (char*)d_ws;
  unsigned short* xb = (unsigned short*)ws;                         // 16MB, reused as ctx
  unsigned short* Wb = (unsigned short*)(ws + (size_t)(16u << 20)); // 8MB (Wp bf16)
  unsigned short* Pq = (unsigned short*)(ws + (size_t)(24u << 20)); // 3x16MB contiguous
  unsigned short* Pk = (unsigned short*)(ws + (size_t)(40u << 20));
  unsigned short* Pv = (unsigned short*)(ws + (size_t)(56u << 20));
  unsigned short* WB3 = (unsigned short*)d_out;  // d_out scratch during QKV

  const int nX4 = ROWSM * EMB / 4;
  const int nW4 = EMB * EMB / 4;

  cvt_all<<<dim3(nX4 / 256, 1, 5), 256, 0, stream>>>(
      x, Wq, Wk, Wv, Wp, xb, WB3, Wb, nX4, nW4);

  gemm192_qkv<<<512, 512, 0, stream>>>(xb, WB3, Pq);

  attn_causal<<<512, 256, 0, stream>>>(Pq, Pk, Pv, xb);

  gemm_p8<<<256, 512, 0, stream>>>(xb, Wb, (float*)d_out, bp);
}

// Round 25
// 256.917 us; speedup vs baseline: 1.0366x; 1.0366x over previous
//
#include <hip/hip_runtime.h>

#define SEQ   2048
#define EMB   2048
#define NHEAD 16
#define HDIM  128
#define ROWSM 4096  // B*SEQ

typedef float  f32x4   __attribute__((ext_vector_type(4)));
typedef float  f32x16  __attribute__((ext_vector_type(16)));
typedef __bf16 bf16x8  __attribute__((ext_vector_type(8)));

__device__ __forceinline__ unsigned short f2bf(float f) {
  union { __bf16 b; unsigned short u; } v; v.b = (__bf16)f; return v.u;
}
__device__ __forceinline__ unsigned int pk2(float a, float b) {
  return (unsigned int)f2bf(a) | ((unsigned int)f2bf(b) << 16);
}
__device__ __forceinline__ float max3f(float a, float b, float c) {
  return fmaxf(fmaxf(a, b), c);   // clang fuses to v_max3_f32 (T17)
}

__device__ __forceinline__ void gload16(const void* g, void* l) {
  __builtin_amdgcn_global_load_lds(
      (__attribute__((address_space(1))) const unsigned int*)g,
      (__attribute__((address_space(3))) unsigned int*)l,
      16, 0, 0);
}

// ALL fp32->bf16 converts in ONE launch (round-18 proven, frozen)
__global__ void cvt_all(const float* __restrict__ x,  const float* __restrict__ Wq,
                        const float* __restrict__ Wk, const float* __restrict__ Wv,
                        const float* __restrict__ Wp, unsigned short* __restrict__ xb,
                        unsigned short* __restrict__ WB3, unsigned short* __restrict__ Wb,
                        int nX4, int nW4) {
  const int z = blockIdx.z;
  const float* in;
  unsigned short* out;
  int n4;
  if (z == 0)      { in = x;  out = xb;  n4 = nX4; }
  else if (z == 1) { in = Wq; out = WB3;                          n4 = nW4; }
  else if (z == 2) { in = Wk; out = WB3 + (size_t)EMB * EMB;      n4 = nW4; }
  else if (z == 3) { in = Wv; out = WB3 + (size_t)2 * EMB * EMB;  n4 = nW4; }
  else             { in = Wp; out = Wb;  n4 = nW4; }
  int i = blockIdx.x * 256 + threadIdx.x;
  if (i >= n4) return;
  float4 v = ((const float4*)in)[i];
  ushort4 o4;
  o4.x = f2bf(v.x); o4.y = f2bf(v.y); o4.z = f2bf(v.z); o4.w = f2bf(v.w);
  ((ushort4*)out)[i] = o4;
}

// ====== QKV fused GEMM: BM=256 x BN=192, N=6144 (round-17 proven, frozen).
// r24's 32x32x16 port regressed (+11us: the ^(row&7) swizzle only covers 8
// slot positions for 32 distinct rows -> 1.05e7 bank conflicts). 16x16x32
// with lc-based reads is the proven conflict-free config. ======
__global__ __launch_bounds__(512, 1) void gemm192_qkv(
    const unsigned short* __restrict__ A, const unsigned short* __restrict__ B,
    unsigned short* __restrict__ Cb) {
  __shared__ __align__(16) unsigned short At[2][256 * 64];  // 64KB
  __shared__ __align__(16) unsigned short Bt[2][192 * 64];  // 48KB

  const int tid  = threadIdx.x;
  const int lane = tid & 63;
  const int w    = tid >> 6;
  const int wr   = w >> 2;
  const int wc   = w & 3;
  const int lg   = lane >> 4;
  const int lc   = lane & 15;

  const int bid = blockIdx.x;
  const int xcd = bid & 7;
  const int j   = bid >> 3;
  const int mt  = xcd * 2 + (j >> 5);
  const int nt  = j & 31;
  const int m0 = mt * 256;
  const int n0 = nt * 192;

  const int srow8 = lane >> 3;
  const int sslot = (lane & 7) ^ srow8;
  const int NT = EMB / 64;

  auto stageAeven = [&](int ts) {
    if (ts >= NT) return;
    int buf = ts & 1, k0 = ts * 64;
    { int c = w;      int row = c * 8 + srow8;
      gload16(A + (size_t)(m0 + row) * EMB + k0 + sslot * 8, (char*)&At[buf][0] + c * 1024); }
    { int c = 16 + w; int row = c * 8 + srow8;
      gload16(A + (size_t)(m0 + row) * EMB + k0 + sslot * 8, (char*)&At[buf][0] + c * 1024); }
  };
  auto stageAodd = [&](int ts) {
    if (ts >= NT) return;
    int buf = ts & 1, k0 = ts * 64;
    { int c = 8 + w;  int row = c * 8 + srow8;
      gload16(A + (size_t)(m0 + row) * EMB + k0 + sslot * 8, (char*)&At[buf][0] + c * 1024); }
    { int c = 24 + w; int row = c * 8 + srow8;
      gload16(A + (size_t)(m0 + row) * EMB + k0 + sslot * 8, (char*)&At[buf][0] + c * 1024); }
  };
  auto stageB = [&](int ts) {
    if (ts >= NT) return;
    int buf = ts & 1, k0 = ts * 64;
#pragma unroll
    for (int s = 0; s < 3; ++s) {
      int c = w + s * 8;
      int row = c * 8 + srow8;
      gload16(B + (size_t)(n0 + row) * EMB + k0 + sslot * 8, (char*)&Bt[buf][0] + c * 1024);
    }
  };

  f32x4 acc[8][3] = {};
  bf16x8 afr[4][2], bfr[3][2];

  stageAeven(0); stageB(0); stageAodd(0); stageAeven(1); stageB(1);
  asm volatile("s_waitcnt vmcnt(7)" ::: "memory");
  __builtin_amdgcn_s_barrier();

  for (int t = 0; t < NT; ++t) {
    const char* ab = (const char*)&At[t & 1][0];
    const char* bb = (const char*)&Bt[t & 1][0];

#pragma unroll
    for (int ni = 0; ni < 3; ++ni)
#pragma unroll
      for (int kk = 0; kk < 2; ++kk) {
        int row = wc * 48 + ni * 16 + lc;
        bfr[ni][kk] = *(const bf16x8*)(bb + row * 128 + ((((kk << 2) | lg) ^ (lc & 7)) << 4));
      }
#pragma unroll
    for (int mi = 0; mi < 4; ++mi)
#pragma unroll
      for (int kk = 0; kk < 2; ++kk) {
        int row = wr * 128 + mi * 16 + lc;
        afr[mi][kk] = *(const bf16x8*)(ab + row * 128 + ((((kk << 2) | lg) ^ (lc & 7)) << 4));
      }
    stageAodd(t + 1);
    __builtin_amdgcn_s_barrier();
    asm volatile("s_waitcnt lgkmcnt(0)" ::: "memory");
    __builtin_amdgcn_sched_barrier(0);
    __builtin_amdgcn_s_setprio(1);
#pragma unroll
    for (int mi = 0; mi < 4; ++mi)
#pragma unroll
      for (int ni = 0; ni < 3; ++ni)
#pragma unroll
        for (int kk = 0; kk < 2; ++kk)
          acc[mi][ni] = __builtin_amdgcn_mfma_f32_16x16x32_bf16(
              afr[mi][kk], bfr[ni][kk], acc[mi][ni], 0, 0, 0);
    __builtin_amdgcn_s_setprio(0);
    if (t + 1 < NT) asm volatile("s_waitcnt vmcnt(7)" ::: "memory");
    else            asm volatile("s_waitcnt vmcnt(0)" ::: "memory");
    __builtin_amdgcn_s_barrier();

#pragma unroll
    for (int mi = 0; mi < 4; ++mi)
#pragma unroll
      for (int kk = 0; kk < 2; ++kk) {
        int row = wr * 128 + 64 + mi * 16 + lc;
        afr[mi][kk] = *(const bf16x8*)(ab + row * 128 + ((((kk << 2) | lg) ^ (lc & 7)) << 4));
      }
    stageAeven(t + 2); stageB(t + 2);
    __builtin_amdgcn_s_barrier();
    asm volatile("s_waitcnt lgkmcnt(0)" ::: "memory");
    __builtin_amdgcn_sched_barrier(0);
    __builtin_amdgcn_s_setprio(1);
#pragma unroll
    for (int mi = 0; mi < 4; ++mi)
#pragma unroll
      for (int ni = 0; ni < 3; ++ni)
#pragma unroll
        for (int kk = 0; kk < 2; ++kk)
          acc[4 + mi][ni] = __builtin_amdgcn_mfma_f32_16x16x32_bf16(
              afr[mi][kk], bfr[ni][kk], acc[4 + mi][ni], 0, 0, 0);
    __builtin_amdgcn_s_setprio(0);
    if (t + 2 < NT)      asm volatile("s_waitcnt vmcnt(7)" ::: "memory");
    else if (t + 1 < NT) asm volatile("s_waitcnt vmcnt(2)" ::: "memory");
    __builtin_amdgcn_s_barrier();
  }

#pragma unroll
  for (int mi = 0; mi < 8; ++mi)
#pragma unroll
    for (int ni = 0; ni < 3; ++ni) {
      int col = n0 + wc * 48 + ni * 16 + lc;
      unsigned short* dst = Cb + (size_t)(col >> 11) * ROWSM * EMB + (col & 2047);
#pragma unroll
      for (int rr = 0; rr < 4; ++rr) {
        int row = m0 + wr * 128 + mi * 16 + lg * 4 + rr;
        dst[(size_t)row * EMB] = f2bf(acc[mi][ni][rr]);
      }
    }
}

// ====== Final projection GEMM: BM=128 x BN=256 (round-15 proven, frozen) =====
__global__ __launch_bounds__(512, 1) void gemm_p8(
    const unsigned short* __restrict__ A, const unsigned short* __restrict__ B,
    float* __restrict__ Cout, const float* __restrict__ bias) {
  __shared__ __align__(16) unsigned short At[2][128 * 64];
  __shared__ __align__(16) unsigned short Bt[2][256 * 64];

  const int tid  = threadIdx.x;
  const int lane = tid & 63;
  const int w    = tid >> 6;
  const int wr   = w >> 2;
  const int wc   = w & 3;
  const int lg   = lane >> 4;
  const int lc   = lane & 15;

  const int bid = blockIdx.x;
  const int xcd = bid & 7;
  const int j   = bid >> 3;
  const int mt  = xcd * 4 + (j >> 3);
  const int nt  = j & 7;
  const int m0 = mt * 128;
  const int n0 = nt * 256;

  const int srow8 = lane >> 3;
  const int sslot = (lane & 7) ^ srow8;
  const int NT = EMB / 64;

  auto stageA = [&](int ts) {
    if (ts >= NT) return;
    int buf = ts & 1, k0 = ts * 64;
#pragma unroll
    for (int rr = 0; rr < 2; ++rr) {
      int c = w + rr * 8;
      int row = c * 8 + srow8;
      gload16(A + (size_t)(m0 + row) * EMB + k0 + sslot * 8, (char*)&At[buf][0] + c * 1024);
    }
  };
  auto stageBlow = [&](int ts) {
    if (ts >= NT) return;
    int buf = ts & 1, k0 = ts * 64;
#pragma unroll
    for (int rr = 0; rr < 2; ++rr) {
      int i = w + rr * 8;
      int c = (i >> 2) * 8 + (i & 3);
      int row = c * 8 + srow8;
      gload16(B + (size_t)(n0 + row) * EMB + k0 + sslot * 8, (char*)&Bt[buf][0] + c * 1024);
    }
  };
  auto stageBhigh = [&](int ts) {
    if (ts >= NT) return;
    int buf = ts & 1, k0 = ts * 64;
#pragma unroll
    for (int rr = 0; rr < 2; ++rr) {
      int i = w + rr * 8;
      int c = (i >> 2) * 8 + 4 + (i & 3);
      int row = c * 8 + srow8;
      gload16(B + (size_t)(n0 + row) * EMB + k0 + sslot * 8, (char*)&Bt[buf][0] + c * 1024);
    }
  };

  f32x4 acc[4][4] = {};
  bf16x8 afr[4][2], bfr0[2][2], bfr1[2][2];

  stageA(0); stageBlow(0); stageBhigh(0); stageA(1); stageBlow(1);
  asm volatile("s_waitcnt vmcnt(6)" ::: "memory");
  __builtin_amdgcn_s_barrier();

  for (int t = 0; t < NT; ++t) {
    const char* ab = (const char*)&At[t & 1][0];
    const char* bb = (const char*)&Bt[t & 1][0];

#pragma unroll
    for (int ni = 0; ni < 2; ++ni)
#pragma unroll
      for (int kk = 0; kk < 2; ++kk) {
        int row = wc * 64 + ni * 16 + lc;
        bfr0[ni][kk] = *(const bf16x8*)(bb + row * 128 + ((((kk << 2) | lg) ^ (lc & 7)) << 4));
      }
#pragma unroll
    for (int mi = 0; mi < 4; ++mi)
#pragma unroll
      for (int kk = 0; kk < 2; ++kk) {
        int row = wr * 64 + mi * 16 + lc;
        afr[mi][kk] = *(const bf16x8*)(ab + row * 128 + ((((kk << 2) | lg) ^ (lc & 7)) << 4));
      }
    stageBhigh(t + 1);
    __builtin_amdgcn_s_barrier();
    asm volatile("s_waitcnt lgkmcnt(0)" ::: "memory");
    __builtin_amdgcn_sched_barrier(0);
    __builtin_amdgcn_s_setprio(1);
#pragma unroll
    for (int mi = 0; mi < 4; ++mi)
#pragma unroll
      for (int ni = 0; ni < 2; ++ni)
#pragma unroll
        for (int kk = 0; kk < 2; ++kk)
          acc[mi][ni] = __builtin_amdgcn_mfma_f32_16x16x32_bf16(
              afr[mi][kk], bfr0[ni][kk], acc[mi][ni], 0, 0, 0);
    __builtin_amdgcn_s_setprio(0);
    if (t + 1 < NT) asm volatile("s_waitcnt vmcnt(6)" ::: "memory");
    else            asm volatile("s_waitcnt vmcnt(0)" ::: "memory");
    __builtin_amdgcn_s_barrier();

#pragma unroll
    for (int ni = 0; ni < 2; ++ni)
#pragma unroll
      for (int kk = 0; kk < 2; ++kk) {
        int row = wc * 64 + 32 + ni * 16 + lc;
        bfr1[ni][kk] = *(const bf16x8*)(bb + row * 128 + ((((kk << 2) | lg) ^ (lc & 7)) << 4));
      }
    stageA(t + 2); stageBlow(t + 2);
    __builtin_amdgcn_s_barrier();
    asm volatile("s_waitcnt lgkmcnt(0)" ::: "memory");
    __builtin_amdgcn_sched_barrier(0);
    __builtin_amdgcn_s_setprio(1);
#pragma unroll
    for (int mi = 0; mi < 4; ++mi)
#pragma unroll
      for (int ni = 0; ni < 2; ++ni)
#pragma unroll
        for (int kk = 0; kk < 2; ++kk)
          acc[mi][2 + ni] = __builtin_amdgcn_mfma_f32_16x16x32_bf16(
              afr[mi][kk], bfr1[ni][kk], acc[mi][2 + ni], 0, 0, 0);
    __builtin_amdgcn_s_setprio(0);
    if (t + 2 < NT)      asm volatile("s_waitcnt vmcnt(6)" ::: "memory");
    else if (t + 1 < NT) asm volatile("s_waitcnt vmcnt(2)" ::: "memory");
    __builtin_amdgcn_s_barrier();
  }

#pragma unroll
  for (int mi = 0; mi < 4; ++mi)
#pragma unroll
    for (int ni = 0; ni < 4; ++ni) {
      int col = n0 + wc * 64 + ((ni >> 1) * 32) + (ni & 1) * 16 + lc;
#pragma unroll
      for (int rr = 0; rr < 4; ++rr) {
        int row = m0 + wr * 64 + mi * 16 + lg * 4 + rr;
        Cout[(size_t)row * EMB + col] = acc[mi][ni][rr] + bias[col];
      }
    }
}

// ====== Causal flash attention (round-21 PASSING 257us state, frozen) ======
__global__ __launch_bounds__(256, 2) void attn_causal(
    const unsigned short* __restrict__ Pq, const unsigned short* __restrict__ Pk,
    const unsigned short* __restrict__ Pv, unsigned short* __restrict__ ctx) {
  __shared__ __align__(16) unsigned short Ks[2][64 * 128];   // swizzled
  __shared__ __align__(16) unsigned short Vt[2][128 * 64];   // swizzled

  const int tid  = threadIdx.x;
  const int lane = tid & 63;
  const int w    = tid >> 6;
  const int ql   = lane & 31;
  const int hi   = lane >> 5;
  const int lg   = lane >> 4;
  const int lc   = lane & 15;

  const int bid = blockIdx.x;
  const int xcd = bid & 7;
  const int jj_ = bid >> 3;
  const int hh  = jj_ >> 4;
  const int bh  = xcd * 4 + hh;
  const int b   = bh >> 4;
  const int h   = bh & 15;
  const int qtr = jj_ & 15;
  const int qt  = (hh >= 2) ? (15 - qtr) : qtr;
  const int q0 = qt * 128;
  const int qw = q0 + w * 32;
  const int qg = qw + ql;

  const size_t hoff = (size_t)bh * SEQ * HDIM;
  const unsigned short* Q  = Pq + hoff;
  const unsigned short* Kh = Pk + hoff;
  const unsigned short* Vh = Pv + hoff;

  bf16x8 bq[8];
#pragma unroll
  for (int d8 = 0; d8 < 8; ++d8)
    bq[d8] = *(const bf16x8*)(Q + (size_t)qg * HDIM + d8 * 16 + hi * 8);

  const float NEG = -3.0e38f;
  f32x16 o[4];
#pragma unroll
  for (int dt = 0; dt < 4; ++dt)
#pragma unroll
    for (int r = 0; r < 16; ++r) o[dt][r] = 0.f;
  float m_r = NEG, l_r = 0.f;

  const float Cs   = 0.12753123161692858f;
  const float TDEF = 62.7f;

  auto stageK = [&](int buf, int t) {
    int kv0 = t * 64;
#pragma unroll
    for (int ii = 0; ii < 4; ++ii) {
      int i = w * 4 + ii;
      int r = i * 4 + lg;
      int sd = lc ^ (r & 7);
      gload16(Kh + (size_t)(kv0 + r) * HDIM + sd * 8, (char*)&Ks[buf][0] + i * 1024);
    }
  };
  auto loadV = [&](uint4* vr, int t) {
    int kv0 = t * 64;
#pragma unroll
    for (int uu = 0; uu < 2; ++uu) {
      int u = tid + uu * 256;
      int kp = u >> 4, dg = u & 15;
      int k = kp * 2, d0 = dg * 8;
      vr[uu * 2]     = *(const uint4*)(Vh + (size_t)(kv0 + k) * HDIM + d0);
      vr[uu * 2 + 1] = *(const uint4*)(Vh + (size_t)(kv0 + k + 1) * HDIM + d0);
    }
  };
  auto packV = [&](int buf, const uint4* vr) {
#pragma unroll
    for (int uu = 0; uu < 2; ++uu) {
      int u = tid + uu * 256;
      int kp = u >> 4, dg = u & 15;
      int k = kp * 2, d0 = dg * 8;
      const unsigned short* e0 = (const unsigned short*)&vr[uu * 2];
      const unsigned short* e1 = (const unsigned short*)&vr[uu * 2 + 1];
#pragma unroll
      for (int jj = 0; jj < 8; ++jj) {
        int d = d0 + jj;
        int slot = (k >> 3) ^ jj ^ (dg & 7);
        int byteoff = d * 128 + (slot << 4) + (k & 7) * 2;
        *(unsigned int*)((char*)&Vt[buf][0] + byteoff) =
            (unsigned int)e0[jj] | ((unsigned int)e1[jj] << 16);
      }
    }
  };

  const int ntiles = 2 * qt + 2;
  uint4 vr[4];

  loadV(vr, 0); stageK(0, 0);
  asm volatile("s_waitcnt vmcnt(4)" ::: "memory");
  packV(0, vr);
  loadV(vr, 1); stageK(1, 1);
  asm volatile("s_waitcnt vmcnt(8)" ::: "memory");
  asm volatile("s_waitcnt lgkmcnt(0)" ::: "memory");
  __builtin_amdgcn_s_barrier();

  for (int t = 0; t < ntiles; ++t) {
    const int buf = t & 1;
    const bool hasN1 = (t + 1 < ntiles);
    const bool hasN2 = (t + 2 < ntiles);
    const int kv0 = t * 64;

    if (hasN1) {
      asm volatile("s_waitcnt vmcnt(4)" ::: "memory");
      packV(buf ^ 1, vr);
      if (hasN2) loadV(vr, t + 2);
    }

    if (kv0 <= qw + 31) {
      const bool s1on = (kv0 + 32 <= qw + 31);
      const bool diag = (kv0 + 63 > qw);
      const char* ksb = (const char*)&Ks[buf][0];
      const char* vtb = (const char*)&Vt[buf][0];

      f32x16 c0, c1;
#pragma unroll
      for (int r = 0; r < 16; ++r) { c0[r] = 0.f; c1[r] = s1on ? 0.f : NEG; }
      __builtin_amdgcn_s_setprio(1);
#pragma unroll
      for (int d8 = 0; d8 < 8; ++d8) {
        bf16x8 ak = *(const bf16x8*)(ksb + ql * 256 +
                                     (((d8 * 2 + hi) ^ (ql & 7)) << 4));
        c0 = __builtin_amdgcn_mfma_f32_32x32x16_bf16(ak, bq[d8], c0, 0, 0, 0);
      }
      if (s1on) {
#pragma unroll
        for (int d8 = 0; d8 < 8; ++d8) {
          bf16x8 ak = *(const bf16x8*)(ksb + (32 + ql) * 256 +
                                       (((d8 * 2 + hi) ^ (ql & 7)) << 4));
          c1 = __builtin_amdgcn_mfma_f32_32x32x16_bf16(ak, bq[d8], c1, 0, 0, 0);
        }
      }
      __builtin_amdgcn_s_setprio(0);

      if (diag) {
#pragma unroll
        for (int r = 0; r < 16; ++r) {
          int kvl = (r & 3) + 8 * (r >> 2) + 4 * hi;
          if (kv0 + kvl > qg) c0[r] = NEG;
          if (s1on && kv0 + 32 + kvl > qg) c1[r] = NEG;
        }
      }
      float rm;
      {
        float a0 = max3f(c0[0],  c0[1],  c0[2]);
        float a1 = max3f(c0[3],  c0[4],  c0[5]);
        float a2 = max3f(c0[6],  c0[7],  c0[8]);
        float a3 = max3f(c0[9],  c0[10], c0[11]);
        float a4 = max3f(c0[12], c0[13], c0[14]);
        float a5 = max3f(c0[15], c1[0],  c1[1]);
        float a6 = max3f(c1[2],  c1[3],  c1[4]);
        float a7 = max3f(c1[5],  c1[6],  c1[7]);
        float a8 = max3f(c1[8],  c1[9],  c1[10]);
        float a9 = max3f(c1[11], c1[12], c1[13]);
        float aa = fmaxf(c1[14], c1[15]);
        float b0 = max3f(a0, a1, a2);
        float b1 = max3f(a3, a4, a5);
        float b2 = max3f(a6, a7, a8);
        float b3 = max3f(a9, aa, NEG);
        rm = fmaxf(fmaxf(b0, b1), fmaxf(b2, b3));
      }
      rm = fmaxf(rm, __shfl_xor(rm, 32));

      if (__any(rm > m_r + TDEF)) {       // T13 defer-max
        float mnew = fmaxf(m_r, rm);
        float alpha = exp2f((m_r - mnew) * Cs);
        m_r = mnew;
        l_r *= alpha;
#pragma unroll
        for (int r = 0; r < 16; ++r) {
          float ar = __shfl(alpha, (r & 3) + 8 * (r >> 2) + 4 * hi);
#pragma unroll
          for (int dt = 0; dt < 4; ++dt) o[dt][r] *= ar;
        }
      }
#pragma unroll
      for (int r = 0; r < 16; ++r) {
        c0[r] = exp2f((c0[r] - m_r) * Cs);
        c1[r] = exp2f((c1[r] - m_r) * Cs);
      }
      float ps = 0.f;
#pragma unroll
      for (int r = 0; r < 16; ++r) ps += c0[r] + c1[r];
      ps += __shfl_xor(ps, 32);
      l_r += ps;

      bf16x8 pa[4];
#pragma unroll
      for (int t4 = 0; t4 < 4; ++t4) {
        const f32x16& cc = (t4 < 2) ? c0 : c1;
        const int rA = (t4 & 1) * 8;
        unsigned int pkL0 = pk2(cc[rA + 0], cc[rA + 1]);
        unsigned int pkL1 = pk2(cc[rA + 2], cc[rA + 3]);
        unsigned int pkH0 = pk2(cc[rA + 4], cc[rA + 5]);
        unsigned int pkH1 = pk2(cc[rA + 6], cc[rA + 7]);
        unsigned int give0 = hi ? pkL0 : pkH0;
        unsigned int give1 = hi ? pkL1 : pkH1;
        unsigned int keep0 = hi ? pkH0 : pkL0;
        unsigned int keep1 = hi ? pkH1 : pkL1;
        unsigned int recv0 = __shfl_xor(give0, 32);
        unsigned int recv1 = __shfl_xor(give1, 32);
        union { unsigned int u[4]; bf16x8 v; } pu;
        pu.u[0] = hi ? recv0 : keep0;
        pu.u[1] = hi ? recv1 : keep1;
        pu.u[2] = hi ? keep0 : recv0;
        pu.u[3] = hi ? keep1 : recv1;
        pa[t4] = pu.v;
      }
      __builtin_amdgcn_s_setprio(1);
#pragma unroll
      for (int t4 = 0; t4 < 4; ++t4) {
        if (diag && kv0 + t4 * 16 > qw + 31) continue;
#pragma unroll
        for (int dt = 0; dt < 4; ++dt) {
          int d = dt * 32 + ql;
          int slot = ((t4 << 1) | hi) ^ (d & 7) ^ ((d >> 3) & 7);
          bf16x8 bv = *(const bf16x8*)(vtb + d * 128 + (slot << 4));
          o[dt] = __builtin_amdgcn_mfma_f32_32x32x16_bf16(pa[t4], bv, o[dt], 0, 0, 0);
        }
      }
      __builtin_amdgcn_s_setprio(0);
    }

    if (hasN2) stageK(buf, t + 2);
    asm volatile("s_waitcnt lgkmcnt(0)" ::: "memory");
    if (hasN1) {
      if (hasN2) asm volatile("s_waitcnt vmcnt(8)" ::: "memory");
      else       asm volatile("s_waitcnt vmcnt(0)" ::: "memory");
    }
    __builtin_amdgcn_s_barrier();
  }

  float linv = 1.0f / l_r;
  unsigned short* outp = ctx + (size_t)b * SEQ * EMB + (size_t)h * HDIM;
#pragma unroll
  for (int r = 0; r < 16; ++r) {
    int kvl = (r & 3) + 8 * (r >> 2) + 4 * hi;
    float lr = __shfl(linv, kvl);
    int qrow = qw + kvl;
#pragma unroll
    for (int dt = 0; dt < 4; ++dt)
      outp[(size_t)qrow * EMB + dt * 32 + ql] = f2bf(o[dt][r] * lr);
  }
}

extern "C" void kernel_launch(void* const* d_in, const int* in_sizes, int n_in,
                              void* d_out, int out_size, void* d_ws, size_t ws_size,
                              hipStream_t stream) {
  const float* x  = (const float*)d_in[0];
  const float* Wq = (const float*)d_in[1];
  const float* Wk = (const float*)d_in[2];
  const float* Wv = (const float*)d_in[3];
  const float* Wp = (const float*)d_in[4];
  const float* bp = (const float*)d_in[5];

  char* ws = (char*)d_ws;
  unsigned short* xb = (unsigned short*)ws;                         // 16MB, reused as ctx
  unsigned short* Wb = (unsigned short*)(ws + (size_t)(16u << 20)); // 8MB (Wp bf16)
  unsigned short* Pq = (unsigned short*)(ws + (size_t)(24u << 20)); // 3x16MB contiguous
  unsigned short* Pk = (unsigned short*)(ws + (size_t)(40u << 20));
  unsigned short* Pv = (unsigned short*)(ws + (size_t)(56u << 20));
  unsigned short* WB3 = (unsigned short*)d_out;  // d_out scratch during QKV

  const int nX4 = ROWSM * EMB / 4;
  const int nW4 = EMB * EMB / 4;

  cvt_all<<<dim3(nX4 / 256, 1, 5), 256, 0, stream>>>(
      x, Wq, Wk, Wv, Wp, xb, WB3, Wb, nX4, nW4);

  gemm192_qkv<<<512, 512, 0, stream>>>(xb, WB3, Pq);

  attn_causal<<<512, 256, 0, stream>>>(Pq, Pk, Pv, xb);

  gemm_p8<<<256, 512, 0, stream>>>(xb, Wb, (float*)d_out, bp);
}